// Round 9
// baseline (544.501 us; speedup 1.0000x reference)
//
#include <hip/hip_runtime.h>

#define NCH 6
#define NX 32
#define PLANE 1024                  // 32x32 cells per x-plane
#define NCELL (NX * PLANE)
#define STEP_STRIDE (NCH * NCELL)   // floats per history slice
#define NTHREADS 256                // one y-stripe (8 rows x 32 z) of a plane
#define NBLOCKS 128                 // 32 planes x 4 y-stripes
#define RB 2                        // ring slots (epoch&1); sign-bit parity disambiguates

// ws: u64 ring[RB][3][NCELL] SoA streams (stream k = channels 2k,2k+1), then
// int flags. Epoch tag = sign bits: phi in [0,1] post-clip -> sign always 0;
// producer ORs parity P=((e)>>1)&1 into both sign bits. (slot,P) uniquely ids
// epoch e vs e+-2; mutual neighbor dependency bounds skew<=1 so +-4 unreachable.
// Poison 0xAA.. has sign=1: misses all parity-0 epochs, and every record is
// rewritten by a real epoch before its first parity-1 check -> bootstrap-safe.
#define RING_WORDS ((size_t)RB * 3 * NCELL)
#define F_DONE 0

typedef unsigned long long u64;

__device__ __forceinline__ u64 ld64(const u64* p) {
    return __hip_atomic_load(p, __ATOMIC_RELAXED, __HIP_MEMORY_SCOPE_SYSTEM);
}
__device__ __forceinline__ void st64(u64* p, u64 v) {
    __hip_atomic_store(p, v, __ATOMIC_RELAXED, __HIP_MEMORY_SCOPE_SYSTEM);
}
__device__ __forceinline__ int ldi(const int* p) {
    return __hip_atomic_load(p, __ATOMIC_RELAXED, __HIP_MEMORY_SCOPE_SYSTEM);
}
__device__ __forceinline__ void sti(int* p, int v) {
    __hip_atomic_store(p, v, __ATOMIC_RELAXED, __HIP_MEMORY_SCOPE_SYSTEM);
}
__device__ __forceinline__ u64 pack2p(float a, float b, unsigned P) {
    const u64 w = ((u64)__float_as_uint(b) << 32) | __float_as_uint(a);
    return P ? (w | 0x8000000080000000ULL) : w;
}
__device__ __forceinline__ bool tagok(u64 w, unsigned P) {
    return (((unsigned)(w >> 63)) == P) & ((((unsigned)w) >> 31) == P);
}

// try one tagged u64: on parity hit, strip sign bits and clear pend bit
#define TRY(bit, ptr, d0, d1)                                                  \
    if (pend & (bit)) {                                                        \
        const u64 w_ = ld64(ptr);                                              \
        if (tagok(w_, P)) {                                                    \
            d0 = __uint_as_float((unsigned)w_ & 0x7fffffffu);                  \
            d1 = __uint_as_float((unsigned)(w_ >> 32) & 0x7fffffffu);          \
            pend &= ~(bit);                                                    \
        }                                                                      \
    }

// Tagged-dataflow stepper: producer fire-and-forgets 3 tagged u64/cell (no
// drain, no flag store); consumer polls the data words themselves -> ONE L3
// round-trip per step on the critical path (R8 had three: drain, flag poll,
// data load). Done-flag polled concurrently by lane0 of each wave (plain
// reads, off critical path); overshoot past freeze is harmless (fill
// overwrites slices > t*). One __syncthreads/step gates tile ping-pong.
__global__ void __launch_bounds__(NTHREADS)
BEMNA_V7_2_PhaseSpace_44117904064519_kernel(
    const float* __restrict__ D,
    const int* __restrict__ sx_p, const int* __restrict__ sy_p,
    const int* __restrict__ sz_p, const int* __restrict__ ex_p,
    const int* __restrict__ ey_p, const int* __restrict__ ez_p,
    const int* __restrict__ maxit_p,
    float* __restrict__ out,
    u64* __restrict__ ring,
    int* __restrict__ flags)
{
    __shared__ float tile[2][NCH][NTHREADS];   // ping-pong own stripe
    __shared__ int lds_dn;
    volatile int* vdn = &lds_dn;

    const int tid = (int)threadIdx.x;          // yl*32+z
    const int bx  = (int)blockIdx.x;
    const int x   = bx >> 2;                   // plane
    const int s   = bx & 3;                    // y-stripe
    const int yl  = tid >> 5;                  // 0..7
    const int z   = tid & 31;
    const int y   = (s << 3) + yl;
    const int cell = (x << 10) + (y << 5) + z;

    const int sx = *sx_p, sy = *sy_p, sz = *sz_p;
    const int ex = *ex_p, ey = *ey_p, ez = *ez_p;
    const int maxit = *maxit_p;
    const bool is_seed   = (cell == ((sx << 10) | (sy << 5) | sz));
    const bool is_target = (cell == ((ex << 10) | (ey << 5) | ez));

    // o=0 reads (x-1); o=1 (x+1); o=2 (y-1); o=3 (y+1); o=4 (z-1); o=5 (z+1)
    const int  nbg[NCH] = { cell - PLANE, cell + PLANE, cell - 32, cell + 32, cell - 1, cell + 1 };
    const bool ok[NCH]  = { x >= 1, x <= 30, y >= 1, y <= 30, z >= 1, z <= 30 };
    const int izm = (tid - 1) & (NTHREADS - 1), izp = (tid + 1) & (NTHREADS - 1);

    // halo groups this thread needs from the ring
    const bool has_xm = (x >= 1), has_xp = (x <= 30);
    const bool has_ym = (yl == 0) && (y >= 1);
    const bool has_yp = (yl == 7) && (y <= 30);
    const int base_pend = (has_xm ? 0x007 : 0) | (has_xp ? 0x038 : 0)
                        | (has_ym ? 0x1C0 : 0) | (has_yp ? 0xE00 : 0);

    // D step-invariant: 36 coefficients in registers (zeroed out-of-bounds)
    float dreg[NCH][NCH];
#pragma unroll
    for (int o = 0; o < NCH; ++o)
#pragma unroll
        for (int i = 0; i < NCH; ++i)
            dreg[o][i] = ok[o] ? D[(size_t)(o * NCH + i) * NCELL + nbg[o]] + 0.95f : 0.0f;

    // ---- init: epoch 0 (slot 0, parity 0 = plain), hist slice 0, tile[0] ----
    const float iv = is_seed ? 1.0f : 0.0f;
    {
        const u64 p = pack2p(iv, iv, 0);
        st64(&ring[0 * NCELL + cell], p);
        st64(&ring[1 * NCELL + cell], p);
        st64(&ring[2 * NCELL + cell], p);
        float* outp = out + cell;
#pragma unroll
        for (int o = 0; o < NCH; ++o) { outp[o * NCELL] = iv; tile[0][o][tid] = iv; }
    }
    if (tid == 0) lds_dn = -1;
    __syncthreads();                           // lds_dn + tile[0] visible

    int tripped = 0;
    // iteration t consumes epoch t, produces phi_{t+1} (= history slice t+1)
    for (int t = 0; t <= maxit - 2; ++t) {
        const u64* r0 = ring + (size_t)(t & 1) * 3 * NCELL;
        const u64* r1 = r0 + NCELL;
        const u64* r2 = r1 + NCELL;
        const unsigned P = (unsigned)((t >> 1) & 1);

        float xm[NCH] = {0,0,0,0,0,0}, xp[NCH] = {0,0,0,0,0,0};
        float ym[NCH] = {0,0,0,0,0,0}, yp[NCH] = {0,0,0,0,0,0};
        int pend = base_pend;
        const int cm = cell - PLANE, cp = cell + PLANE;
        const int am = cell - 32,    ap = cell + 32;

        for (;;) {
            TRY(0x001, r0 + cm, xm[0], xm[1])
            TRY(0x002, r1 + cm, xm[2], xm[3])
            TRY(0x004, r2 + cm, xm[4], xm[5])
            TRY(0x008, r0 + cp, xp[0], xp[1])
            TRY(0x010, r1 + cp, xp[2], xp[3])
            TRY(0x020, r2 + cp, xp[4], xp[5])
            TRY(0x040, r0 + am, ym[0], ym[1])
            TRY(0x080, r1 + am, ym[2], ym[3])
            TRY(0x100, r2 + am, ym[4], ym[5])
            TRY(0x200, r0 + ap, yp[0], yp[1])
            TRY(0x400, r1 + ap, yp[2], yp[3])
            TRY(0x800, r2 + ap, yp[4], yp[5])

            if ((tid & 63) == 0) {             // lane0/wave: done duty
                const int dn = ldi(&flags[F_DONE]);
                if (dn >= 0) *vdn = dn;
            }
            const int d = *vdn;                // LDS broadcast, wave-uniform
            if (d >= 0 && t + 1 > d) break;    // abort: data moot
            if (__ballot(pend == 0) == ~0ull) break;
            __builtin_amdgcn_s_sleep(1);
        }
        __syncthreads();                       // tile[t&1] complete + vdn settled
        { const int d = *vdn; if (d >= 0 && t + 1 > d) break; }  // uniform abort

        // in-stripe y neighbors from LDS (dreg masks y==0/31 edges)
        const float (*L)[NTHREADS] = tile[t & 1];
        if (!has_ym) {
            const int n = (tid - 32) & (NTHREADS - 1);
#pragma unroll
            for (int i = 0; i < NCH; ++i) ym[i] = L[i][n];
        }
        if (!has_yp) {
            const int n = (tid + 32) & (NTHREADS - 1);
#pragma unroll
            for (int i = 0; i < NCH; ++i) yp[i] = L[i][n];
        }

        float v[NCH];
        {
            float a0 = 0.f, a1 = 0.f, a2 = 0.f, a3 = 0.f, a4 = 0.f, a5 = 0.f;
#pragma unroll
            for (int i = 0; i < NCH; ++i) {
                a0 = fmaf(dreg[0][i], xm[i], a0);
                a1 = fmaf(dreg[1][i], xp[i], a1);
                a2 = fmaf(dreg[2][i], ym[i], a2);
                a3 = fmaf(dreg[3][i], yp[i], a3);
                a4 = fmaf(dreg[4][i], L[i][izm], a4);
                a5 = fmaf(dreg[5][i], L[i][izp], a5);
            }
            v[0] = fminf(fmaxf(a0, 0.f), 1.f);
            v[1] = fminf(fmaxf(a1, 0.f), 1.f);
            v[2] = fminf(fmaxf(a2, 0.f), 1.f);
            v[3] = fminf(fmaxf(a3, 0.f), 1.f);
            v[4] = fminf(fmaxf(a4, 0.f), 1.f);
            v[5] = fminf(fmaxf(a5, 0.f), 1.f);
        }

        // trip: phi_{t+1} is the frozen state -> done_step = t+1
        if (is_target && !tripped) {
            if (v[0] + v[1] + v[2] + v[3] + v[4] + v[5] > 0.01f) {
                sti(&flags[F_DONE], t + 1);
                tripped = 1;
            }
        }

        // publish epoch t+1: fire-and-forget tagged stores (no drain, no flag)
        {
            const unsigned P1 = (unsigned)(((t + 1) >> 1) & 1);
            u64* w0 = ring + (size_t)((t + 1) & 1) * 3 * NCELL;
            st64(w0 + 0 * NCELL + cell, pack2p(v[0], v[1], P1));
            st64(w0 + 1 * NCELL + cell, pack2p(v[2], v[3], P1));
            st64(w0 + 2 * NCELL + cell, pack2p(v[4], v[5], P1));
#pragma unroll
            for (int o = 0; o < NCH; ++o) tile[(t + 1) & 1][o][tid] = v[o];
        }

        // history slice t+1 last: HBM acks overlap the next poll
        {
            float* outp = out + (size_t)(t + 1) * STEP_STRIDE + cell;
#pragma unroll
            for (int o = 0; o < NCH; ++o) outp[o * NCELL] = v[o];
        }
    }
}

// 2D fill: slices t*+1 .. maxit-1 := out[t*] (also rewrites any overshoot
// slices the stepper wrote past the freeze). Whole blocks exit for t <= t*.
__global__ void fill_kernel(const int* __restrict__ flags,
                            float4* __restrict__ out)
{
    const int s4 = STEP_STRIDE / 4;
    const int t = (int)blockIdx.y;
    const int maxit = (int)gridDim.y;
    const int ds = flags[F_DONE];
    const int tf = (ds >= 1 && ds <= maxit - 1) ? ds : maxit - 1;
    if (t <= tf) return;
    const int base = (int)blockIdx.x * 1024 + (int)threadIdx.x;
#pragma unroll
    for (int k = 0; k < 4; ++k) {
        const int off = base + k * 256;
        out[(size_t)t * s4 + off] = out[(size_t)tf * s4 + off];
    }
}

extern "C" void kernel_launch(void* const* d_in, const int* in_sizes, int n_in,
                              void* d_out, int out_size, void* d_ws, size_t ws_size,
                              hipStream_t stream)
{
    const float* D   = (const float*)d_in[0];
    const int* sx    = (const int*)d_in[1];
    const int* sy    = (const int*)d_in[2];
    const int* sz    = (const int*)d_in[3];
    const int* ex    = (const int*)d_in[4];
    const int* ey    = (const int*)d_in[5];
    const int* ez    = (const int*)d_in[6];
    const int* maxit = (const int*)d_in[7];
    float* out = (float*)d_out;

    u64* ring  = (u64*)d_ws;                   // 2 x 3 x 32768 x 8B = 1.6 MB
    int* flags = (int*)(ring + RING_WORDS);

    // 128 blocks x 256 threads (x-plane x y-stripe); plain launch, tagged
    // dataflow sync. Co-residency by capacity (128 blocks << 256 CUs).
    BEMNA_V7_2_PhaseSpace_44117904064519_kernel<<<dim3(NBLOCKS), dim3(NTHREADS), 0, stream>>>(
        D, sx, sy, sz, ex, ey, ez, maxit, out, ring, flags);

    const int slices = out_size / STEP_STRIDE;
    fill_kernel<<<dim3(48, slices), dim3(256), 0, stream>>>(flags, (float4*)out);
}

// Round 10
// 405.134 us; speedup vs baseline: 1.3440x; 1.3440x over previous
//
#include <hip/hip_runtime.h>

#define NCH 6
#define NX 32
#define PLANE 1024                  // 32x32 cells per x-plane
#define NCELL (NX * PLANE)
#define STEP_STRIDE (NCH * NCELL)   // floats per history slice
#define NTHREADS 256                // one y-stripe (8 rows x 32 z) of a plane
#define NBLOCKS 128                 // 32 planes x 4 y-stripes
#define RB 2                        // ring slots; (slot, sign-parity) = epoch mod 4

// ws: u64 ring[RB][3][NCELL] SoA streams (stream k = channels 2k,2k+1), then
// int flags. Epoch tag = sign bits (phi in [0,1] post-clip -> sign always 0):
// producer ORs parity P=(e>>1)&1 into both sign bits; (slot=e&1, P) = e mod 4.
// Mutual neighbor dependency bounds skew<=1, so only {t, t-2} can occupy a
// slot -> 1-bit parity disambiguates (R9-proven, absmax 0). Poison 0xAA..
// has sign=1 and every record is rewritten before its first parity-1 check
// -> bootstrap-safe with zero init. R9's REGRESSION was conditional
// per-word polling (12 serialized L3 RTs/round); here all loads are issued
// unconditionally per round (batched -> 1 RT), tags checked afterwards.
#define RING_WORDS ((size_t)RB * 3 * NCELL)
#define F_DONE 0

typedef unsigned long long u64;

__device__ __forceinline__ u64 ld64(const u64* p) {
    return __hip_atomic_load(p, __ATOMIC_RELAXED, __HIP_MEMORY_SCOPE_SYSTEM);
}
__device__ __forceinline__ void st64(u64* p, u64 v) {
    __hip_atomic_store(p, v, __ATOMIC_RELAXED, __HIP_MEMORY_SCOPE_SYSTEM);
}
__device__ __forceinline__ int ldi(const int* p) {
    return __hip_atomic_load(p, __ATOMIC_RELAXED, __HIP_MEMORY_SCOPE_SYSTEM);
}
__device__ __forceinline__ void sti(int* p, int v) {
    __hip_atomic_store(p, v, __ATOMIC_RELAXED, __HIP_MEMORY_SCOPE_SYSTEM);
}
__device__ __forceinline__ u64 pack2p(float a, float b, unsigned P) {
    const u64 w = ((u64)__float_as_uint(b) << 32) | __float_as_uint(a);
    return P ? (w | 0x8000000080000000ULL) : w;
}
__device__ __forceinline__ bool tagok(u64 w, unsigned P) {
    return (((unsigned)(w >> 63)) == P) & ((((unsigned)w) >> 31) == P);
}
__device__ __forceinline__ void unpack2(u64 w, float* d0, float* d1) {
    *d0 = __uint_as_float((unsigned)w & 0x7fffffffu);
    *d1 = __uint_as_float((unsigned)(w >> 32) & 0x7fffffffu);
}

__global__ void __launch_bounds__(NTHREADS)
BEMNA_V7_2_PhaseSpace_44117904064519_kernel(
    const float* __restrict__ D,
    const int* __restrict__ sx_p, const int* __restrict__ sy_p,
    const int* __restrict__ sz_p, const int* __restrict__ ex_p,
    const int* __restrict__ ey_p, const int* __restrict__ ez_p,
    const int* __restrict__ maxit_p,
    float* __restrict__ out,
    u64* __restrict__ ring,
    int* __restrict__ flags)
{
    __shared__ float tile[2][NCH][NTHREADS];   // ping-pong own stripe
    __shared__ int lds_dn;
    volatile int* vdn = &lds_dn;

    const int tid = (int)threadIdx.x;          // yl*32+z
    const int bx  = (int)blockIdx.x;
    const int x   = bx >> 2;                   // plane
    const int s   = bx & 3;                    // y-stripe
    const int yl  = tid >> 5;                  // 0..7
    const int z   = tid & 31;
    const int y   = (s << 3) + yl;
    const int cell = (x << 10) + (y << 5) + z;

    const int sx = *sx_p, sy = *sy_p, sz = *sz_p;
    const int ex = *ex_p, ey = *ey_p, ez = *ez_p;
    const int maxit = *maxit_p;
    const bool is_seed   = (cell == ((sx << 10) | (sy << 5) | sz));
    const bool is_target = (cell == ((ex << 10) | (ey << 5) | ez));

    // o=0 reads (x-1); o=1 (x+1); o=2 (y-1); o=3 (y+1); o=4 (z-1); o=5 (z+1)
    const int  nbg[NCH] = { cell - PLANE, cell + PLANE, cell - 32, cell + 32, cell - 1, cell + 1 };
    const bool ok[NCH]  = { x >= 1, x <= 30, y >= 1, y <= 30, z >= 1, z <= 30 };
    const int izm = (tid - 1) & (NTHREADS - 1), izp = (tid + 1) & (NTHREADS - 1);

    // halo groups this thread needs from the ring
    const bool has_xm = (x >= 1), has_xp = (x <= 30);
    const bool has_ym = (yl == 0) && (y >= 1);
    const bool has_yp = (yl == 7) && (y <= 30);

    // D step-invariant: 36 coefficients in registers (zeroed out-of-bounds)
    float dreg[NCH][NCH];
#pragma unroll
    for (int o = 0; o < NCH; ++o)
#pragma unroll
        for (int i = 0; i < NCH; ++i)
            dreg[o][i] = ok[o] ? D[(size_t)(o * NCH + i) * NCELL + nbg[o]] + 0.95f : 0.0f;

    // ---- init: epoch 0 (slot 0, parity 0 = plain), hist slice 0, tile[0] ----
    const float iv = is_seed ? 1.0f : 0.0f;
    {
        const u64 p = pack2p(iv, iv, 0);
        st64(&ring[0 * NCELL + cell], p);
        st64(&ring[1 * NCELL + cell], p);
        st64(&ring[2 * NCELL + cell], p);
        float* outp = out + cell;
#pragma unroll
        for (int o = 0; o < NCH; ++o) { outp[o * NCELL] = iv; tile[0][o][tid] = iv; }
    }
    if (tid == 0) lds_dn = -1;
    __syncthreads();                           // lds_dn + tile[0] visible

    int tripped = 0;
    // iteration t consumes epoch t, produces phi_{t+1} (= history slice t+1)
    for (int t = 0; t <= maxit - 2; ++t) {
        const u64* r0 = ring + (size_t)(t & 1) * 3 * NCELL;
        const u64* r1 = r0 + NCELL;
        const u64* r2 = r1 + NCELL;
        const unsigned P = (unsigned)((t >> 1) & 1);
        const int cm = cell - PLANE, cp = cell + PLANE;
        const int am = cell - 32,    ap = cell + 32;

        // zero-init so masked/boundary lanes never feed garbage (NaN x 0)
        u64 wa0 = 0, wa1 = 0, wa2 = 0, wb0 = 0, wb1 = 0, wb2 = 0;
        u64 wc0 = 0, wc1 = 0, wc2 = 0, wd0 = 0, wd1 = 0, wd2 = 0;
        for (;;) {
            // batched independent loads -> one waitcnt, one L3 RT per round
            if (has_xm) { wa0 = ld64(r0 + cm); wa1 = ld64(r1 + cm); wa2 = ld64(r2 + cm); }
            if (has_xp) { wb0 = ld64(r0 + cp); wb1 = ld64(r1 + cp); wb2 = ld64(r2 + cp); }
            if (has_ym) { wc0 = ld64(r0 + am); wc1 = ld64(r1 + am); wc2 = ld64(r2 + am); }
            if (has_yp) { wd0 = ld64(r0 + ap); wd1 = ld64(r1 + ap); wd2 = ld64(r2 + ap); }
            if ((tid & 63) == 0) {             // lane0/wave: done-flag duty
                const int dn = ldi(&flags[F_DONE]);
                if (dn >= 0) *vdn = dn;
            }
            // tag checks AFTER all loads are in flight
            bool okr = true;
            if (has_xm) okr = okr & tagok(wa0, P) & tagok(wa1, P) & tagok(wa2, P);
            if (has_xp) okr = okr & tagok(wb0, P) & tagok(wb1, P) & tagok(wb2, P);
            if (has_ym) okr = okr & tagok(wc0, P) & tagok(wc1, P) & tagok(wc2, P);
            if (has_yp) okr = okr & tagok(wd0, P) & tagok(wd1, P) & tagok(wd2, P);
            const int d = *vdn;                // LDS broadcast
            if (d >= 0 && t + 1 > d) break;    // abort: data moot
            if (__ballot(okr) == ~0ull) break;
            __builtin_amdgcn_s_sleep(1);
        }
        __syncthreads();                       // tile writes settled block-wide
        { const int d = *vdn; if (d >= 0 && t + 1 > d) break; }  // uniform abort

        float xm[NCH], xp[NCH], ym[NCH], yp[NCH];
        unpack2(wa0, &xm[0], &xm[1]); unpack2(wa1, &xm[2], &xm[3]); unpack2(wa2, &xm[4], &xm[5]);
        unpack2(wb0, &xp[0], &xp[1]); unpack2(wb1, &xp[2], &xp[3]); unpack2(wb2, &xp[4], &xp[5]);
        unpack2(wc0, &ym[0], &ym[1]); unpack2(wc1, &ym[2], &ym[3]); unpack2(wc2, &ym[4], &ym[5]);
        unpack2(wd0, &yp[0], &yp[1]); unpack2(wd1, &yp[2], &yp[3]); unpack2(wd2, &yp[4], &yp[5]);

        // in-stripe y neighbors from LDS (dreg masks y==0/31 edges)
        const float (*L)[NTHREADS] = tile[t & 1];
        if (!has_ym) {
            const int n = (tid - 32) & (NTHREADS - 1);
#pragma unroll
            for (int i = 0; i < NCH; ++i) ym[i] = L[i][n];
        }
        if (!has_yp) {
            const int n = (tid + 32) & (NTHREADS - 1);
#pragma unroll
            for (int i = 0; i < NCH; ++i) yp[i] = L[i][n];
        }

        float v[NCH];
        {
            float a0 = 0.f, a1 = 0.f, a2 = 0.f, a3 = 0.f, a4 = 0.f, a5 = 0.f;
#pragma unroll
            for (int i = 0; i < NCH; ++i) {
                a0 = fmaf(dreg[0][i], xm[i], a0);
                a1 = fmaf(dreg[1][i], xp[i], a1);
                a2 = fmaf(dreg[2][i], ym[i], a2);
                a3 = fmaf(dreg[3][i], yp[i], a3);
                a4 = fmaf(dreg[4][i], L[i][izm], a4);
                a5 = fmaf(dreg[5][i], L[i][izp], a5);
            }
            v[0] = fminf(fmaxf(a0, 0.f), 1.f);
            v[1] = fminf(fmaxf(a1, 0.f), 1.f);
            v[2] = fminf(fmaxf(a2, 0.f), 1.f);
            v[3] = fminf(fmaxf(a3, 0.f), 1.f);
            v[4] = fminf(fmaxf(a4, 0.f), 1.f);
            v[5] = fminf(fmaxf(a5, 0.f), 1.f);
        }

        // trip: phi_{t+1} is the frozen state -> done_step = t+1
        if (is_target && !tripped) {
            if (v[0] + v[1] + v[2] + v[3] + v[4] + v[5] > 0.01f) {
                sti(&flags[F_DONE], t + 1);
                tripped = 1;
            }
        }

        // publish epoch t+1: fire-and-forget tagged stores (no drain, no flag)
        {
            const unsigned P1 = (unsigned)(((t + 1) >> 1) & 1);
            u64* w0 = ring + (size_t)((t + 1) & 1) * 3 * NCELL;
            st64(w0 + 0 * NCELL + cell, pack2p(v[0], v[1], P1));
            st64(w0 + 1 * NCELL + cell, pack2p(v[2], v[3], P1));
            st64(w0 + 2 * NCELL + cell, pack2p(v[4], v[5], P1));
#pragma unroll
            for (int o = 0; o < NCH; ++o) tile[(t + 1) & 1][o][tid] = v[o];
        }

        // history slice t+1 last: HBM acks overlap the next poll
        {
            float* outp = out + (size_t)(t + 1) * STEP_STRIDE + cell;
#pragma unroll
            for (int o = 0; o < NCH; ++o) outp[o * NCELL] = v[o];
        }
    }
}

// 2D fill: slices t*+1 .. maxit-1 := out[t*] (also rewrites any overshoot
// slices the stepper wrote past the freeze). Whole blocks exit for t <= t*.
__global__ void fill_kernel(const int* __restrict__ flags,
                            float4* __restrict__ out)
{
    const int s4 = STEP_STRIDE / 4;
    const int t = (int)blockIdx.y;
    const int maxit = (int)gridDim.y;
    const int ds = flags[F_DONE];
    const int tf = (ds >= 1 && ds <= maxit - 1) ? ds : maxit - 1;
    if (t <= tf) return;
    const int base = (int)blockIdx.x * 1024 + (int)threadIdx.x;
#pragma unroll
    for (int k = 0; k < 4; ++k) {
        const int off = base + k * 256;
        out[(size_t)t * s4 + off] = out[(size_t)tf * s4 + off];
    }
}

extern "C" void kernel_launch(void* const* d_in, const int* in_sizes, int n_in,
                              void* d_out, int out_size, void* d_ws, size_t ws_size,
                              hipStream_t stream)
{
    const float* D   = (const float*)d_in[0];
    const int* sx    = (const int*)d_in[1];
    const int* sy    = (const int*)d_in[2];
    const int* sz    = (const int*)d_in[3];
    const int* ex    = (const int*)d_in[4];
    const int* ey    = (const int*)d_in[5];
    const int* ez    = (const int*)d_in[6];
    const int* maxit = (const int*)d_in[7];
    float* out = (float*)d_out;

    u64* ring  = (u64*)d_ws;                   // 2 x 3 x 32768 x 8B = 1.6 MB
    int* flags = (int*)(ring + RING_WORDS);

    // 128 blocks x 256 threads (x-plane x y-stripe); plain launch, tagged
    // dataflow sync. Co-residency by capacity (128 blocks << 256 CUs).
    BEMNA_V7_2_PhaseSpace_44117904064519_kernel<<<dim3(NBLOCKS), dim3(NTHREADS), 0, stream>>>(
        D, sx, sy, sz, ex, ey, ez, maxit, out, ring, flags);

    const int slices = out_size / STEP_STRIDE;
    fill_kernel<<<dim3(48, slices), dim3(256), 0, stream>>>(flags, (float4*)out);
}

// Round 11
// 402.556 us; speedup vs baseline: 1.3526x; 1.0064x over previous
//
#include <hip/hip_runtime.h>

#define NCH 6
#define NX 32
#define PLANE 1024                  // 32x32 cells per x-plane
#define NCELL (NX * PLANE)
#define STEP_STRIDE (NCH * NCELL)   // floats per history slice
#define NTHREADS 256                // one y-stripe (8 rows x 32 z) of a plane
#define NBLOCKS 128                 // 32 planes x 4 y-stripes
#define RB 2                        // ring slots; (slot, sign-parity) = epoch mod 4

// ws: u64 ring[RB][3][NCELL] SoA streams (stream k = channels 2k,2k+1), then
// int flags. Epoch tag = sign bits (phi in [0,1] post-clip -> sign always 0):
// producer ORs parity P=(e>>1)&1 into both sign bits; (slot=e&1, P) = e mod 4.
// Mutual neighbor dependency bounds skew<=1, so only {t, t-2} can occupy a
// slot -> 1-bit parity disambiguates (R9/R10-proven, absmax 0). Poison 0xAA..
// has sign=1 and every record is rewritten before its first parity-1 check
// -> bootstrap-safe with zero init. Loads are issued unconditionally per
// poll round (batched -> 1 L3 RT), tags checked afterwards (R10 lesson;
// R9's conditional per-word polling serialized 12 RTs and regressed).
#define RING_WORDS ((size_t)RB * 3 * NCELL)
#define F_DONE 0

typedef unsigned long long u64;

__device__ __forceinline__ u64 ld64(const u64* p) {
    return __hip_atomic_load(p, __ATOMIC_RELAXED, __HIP_MEMORY_SCOPE_SYSTEM);
}
__device__ __forceinline__ void st64(u64* p, u64 v) {
    __hip_atomic_store(p, v, __ATOMIC_RELAXED, __HIP_MEMORY_SCOPE_SYSTEM);
}
__device__ __forceinline__ int ldi(const int* p) {
    return __hip_atomic_load(p, __ATOMIC_RELAXED, __HIP_MEMORY_SCOPE_SYSTEM);
}
__device__ __forceinline__ void sti(int* p, int v) {
    __hip_atomic_store(p, v, __ATOMIC_RELAXED, __HIP_MEMORY_SCOPE_SYSTEM);
}
__device__ __forceinline__ u64 pack2p(float a, float b, unsigned P) {
    const u64 w = ((u64)__float_as_uint(b) << 32) | __float_as_uint(a);
    return P ? (w | 0x8000000080000000ULL) : w;
}
__device__ __forceinline__ bool tagok(u64 w, unsigned P) {
    return (((unsigned)(w >> 63)) == P) & ((((unsigned)w) >> 31) == P);
}
__device__ __forceinline__ void unpack2(u64 w, float* d0, float* d1) {
    *d0 = __uint_as_float((unsigned)w & 0x7fffffffu);
    *d1 = __uint_as_float((unsigned)(w >> 32) & 0x7fffffffu);
}

// Stepper byte-identical to R10 (180 us, absmax 0). This round's change is
// fill-only, for clean attribution.
__global__ void __launch_bounds__(NTHREADS)
BEMNA_V7_2_PhaseSpace_44117904064519_kernel(
    const float* __restrict__ D,
    const int* __restrict__ sx_p, const int* __restrict__ sy_p,
    const int* __restrict__ sz_p, const int* __restrict__ ex_p,
    const int* __restrict__ ey_p, const int* __restrict__ ez_p,
    const int* __restrict__ maxit_p,
    float* __restrict__ out,
    u64* __restrict__ ring,
    int* __restrict__ flags)
{
    __shared__ float tile[2][NCH][NTHREADS];   // ping-pong own stripe
    __shared__ int lds_dn;
    volatile int* vdn = &lds_dn;

    const int tid = (int)threadIdx.x;          // yl*32+z
    const int bx  = (int)blockIdx.x;
    const int x   = bx >> 2;                   // plane
    const int s   = bx & 3;                    // y-stripe
    const int yl  = tid >> 5;                  // 0..7
    const int z   = tid & 31;
    const int y   = (s << 3) + yl;
    const int cell = (x << 10) + (y << 5) + z;

    const int sx = *sx_p, sy = *sy_p, sz = *sz_p;
    const int ex = *ex_p, ey = *ey_p, ez = *ez_p;
    const int maxit = *maxit_p;
    const bool is_seed   = (cell == ((sx << 10) | (sy << 5) | sz));
    const bool is_target = (cell == ((ex << 10) | (ey << 5) | ez));

    // o=0 reads (x-1); o=1 (x+1); o=2 (y-1); o=3 (y+1); o=4 (z-1); o=5 (z+1)
    const int  nbg[NCH] = { cell - PLANE, cell + PLANE, cell - 32, cell + 32, cell - 1, cell + 1 };
    const bool ok[NCH]  = { x >= 1, x <= 30, y >= 1, y <= 30, z >= 1, z <= 30 };
    const int izm = (tid - 1) & (NTHREADS - 1), izp = (tid + 1) & (NTHREADS - 1);

    // halo groups this thread needs from the ring
    const bool has_xm = (x >= 1), has_xp = (x <= 30);
    const bool has_ym = (yl == 0) && (y >= 1);
    const bool has_yp = (yl == 7) && (y <= 30);

    // D step-invariant: 36 coefficients in registers (zeroed out-of-bounds)
    float dreg[NCH][NCH];
#pragma unroll
    for (int o = 0; o < NCH; ++o)
#pragma unroll
        for (int i = 0; i < NCH; ++i)
            dreg[o][i] = ok[o] ? D[(size_t)(o * NCH + i) * NCELL + nbg[o]] + 0.95f : 0.0f;

    // ---- init: epoch 0 (slot 0, parity 0 = plain), hist slice 0, tile[0] ----
    const float iv = is_seed ? 1.0f : 0.0f;
    {
        const u64 p = pack2p(iv, iv, 0);
        st64(&ring[0 * NCELL + cell], p);
        st64(&ring[1 * NCELL + cell], p);
        st64(&ring[2 * NCELL + cell], p);
        float* outp = out + cell;
#pragma unroll
        for (int o = 0; o < NCH; ++o) { outp[o * NCELL] = iv; tile[0][o][tid] = iv; }
    }
    if (tid == 0) lds_dn = -1;
    __syncthreads();                           // lds_dn + tile[0] visible

    int tripped = 0;
    // iteration t consumes epoch t, produces phi_{t+1} (= history slice t+1)
    for (int t = 0; t <= maxit - 2; ++t) {
        const u64* r0 = ring + (size_t)(t & 1) * 3 * NCELL;
        const u64* r1 = r0 + NCELL;
        const u64* r2 = r1 + NCELL;
        const unsigned P = (unsigned)((t >> 1) & 1);
        const int cm = cell - PLANE, cp = cell + PLANE;
        const int am = cell - 32,    ap = cell + 32;

        // zero-init so masked/boundary lanes never feed garbage (NaN x 0)
        u64 wa0 = 0, wa1 = 0, wa2 = 0, wb0 = 0, wb1 = 0, wb2 = 0;
        u64 wc0 = 0, wc1 = 0, wc2 = 0, wd0 = 0, wd1 = 0, wd2 = 0;
        for (;;) {
            // batched independent loads -> one waitcnt, one L3 RT per round
            if (has_xm) { wa0 = ld64(r0 + cm); wa1 = ld64(r1 + cm); wa2 = ld64(r2 + cm); }
            if (has_xp) { wb0 = ld64(r0 + cp); wb1 = ld64(r1 + cp); wb2 = ld64(r2 + cp); }
            if (has_ym) { wc0 = ld64(r0 + am); wc1 = ld64(r1 + am); wc2 = ld64(r2 + am); }
            if (has_yp) { wd0 = ld64(r0 + ap); wd1 = ld64(r1 + ap); wd2 = ld64(r2 + ap); }
            if ((tid & 63) == 0) {             // lane0/wave: done-flag duty
                const int dn = ldi(&flags[F_DONE]);
                if (dn >= 0) *vdn = dn;
            }
            // tag checks AFTER all loads are in flight
            bool okr = true;
            if (has_xm) okr = okr & tagok(wa0, P) & tagok(wa1, P) & tagok(wa2, P);
            if (has_xp) okr = okr & tagok(wb0, P) & tagok(wb1, P) & tagok(wb2, P);
            if (has_ym) okr = okr & tagok(wc0, P) & tagok(wc1, P) & tagok(wc2, P);
            if (has_yp) okr = okr & tagok(wd0, P) & tagok(wd1, P) & tagok(wd2, P);
            const int d = *vdn;                // LDS broadcast
            if (d >= 0 && t + 1 > d) break;    // abort: data moot
            if (__ballot(okr) == ~0ull) break;
            __builtin_amdgcn_s_sleep(1);
        }
        __syncthreads();                       // tile writes settled block-wide
        { const int d = *vdn; if (d >= 0 && t + 1 > d) break; }  // uniform abort

        float xm[NCH], xp[NCH], ym[NCH], yp[NCH];
        unpack2(wa0, &xm[0], &xm[1]); unpack2(wa1, &xm[2], &xm[3]); unpack2(wa2, &xm[4], &xm[5]);
        unpack2(wb0, &xp[0], &xp[1]); unpack2(wb1, &xp[2], &xp[3]); unpack2(wb2, &xp[4], &xp[5]);
        unpack2(wc0, &ym[0], &ym[1]); unpack2(wc1, &ym[2], &ym[3]); unpack2(wc2, &ym[4], &ym[5]);
        unpack2(wd0, &yp[0], &yp[1]); unpack2(wd1, &yp[2], &yp[3]); unpack2(wd2, &yp[4], &yp[5]);

        // in-stripe y neighbors from LDS (dreg masks y==0/31 edges)
        const float (*L)[NTHREADS] = tile[t & 1];
        if (!has_ym) {
            const int n = (tid - 32) & (NTHREADS - 1);
#pragma unroll
            for (int i = 0; i < NCH; ++i) ym[i] = L[i][n];
        }
        if (!has_yp) {
            const int n = (tid + 32) & (NTHREADS - 1);
#pragma unroll
            for (int i = 0; i < NCH; ++i) yp[i] = L[i][n];
        }

        float v[NCH];
        {
            float a0 = 0.f, a1 = 0.f, a2 = 0.f, a3 = 0.f, a4 = 0.f, a5 = 0.f;
#pragma unroll
            for (int i = 0; i < NCH; ++i) {
                a0 = fmaf(dreg[0][i], xm[i], a0);
                a1 = fmaf(dreg[1][i], xp[i], a1);
                a2 = fmaf(dreg[2][i], ym[i], a2);
                a3 = fmaf(dreg[3][i], yp[i], a3);
                a4 = fmaf(dreg[4][i], L[i][izm], a4);
                a5 = fmaf(dreg[5][i], L[i][izp], a5);
            }
            v[0] = fminf(fmaxf(a0, 0.f), 1.f);
            v[1] = fminf(fmaxf(a1, 0.f), 1.f);
            v[2] = fminf(fmaxf(a2, 0.f), 1.f);
            v[3] = fminf(fmaxf(a3, 0.f), 1.f);
            v[4] = fminf(fmaxf(a4, 0.f), 1.f);
            v[5] = fminf(fmaxf(a5, 0.f), 1.f);
        }

        // trip: phi_{t+1} is the frozen state -> done_step = t+1
        if (is_target && !tripped) {
            if (v[0] + v[1] + v[2] + v[3] + v[4] + v[5] > 0.01f) {
                sti(&flags[F_DONE], t + 1);
                tripped = 1;
            }
        }

        // publish epoch t+1: fire-and-forget tagged stores (no drain, no flag)
        {
            const unsigned P1 = (unsigned)(((t + 1) >> 1) & 1);
            u64* w0 = ring + (size_t)((t + 1) & 1) * 3 * NCELL;
            st64(w0 + 0 * NCELL + cell, pack2p(v[0], v[1], P1));
            st64(w0 + 1 * NCELL + cell, pack2p(v[2], v[3], P1));
            st64(w0 + 2 * NCELL + cell, pack2p(v[4], v[5], P1));
#pragma unroll
            for (int o = 0; o < NCH; ++o) tile[(t + 1) & 1][o][tid] = v[o];
        }

        // history slice t+1 last: HBM acks overlap the next poll
        {
            float* outp = out + (size_t)(t + 1) * STEP_STRIDE + cell;
#pragma unroll
            for (int o = 0; o < NCH; ++o) outp[o * NCELL] = v[o];
        }
    }
}

// Read-once/write-many fill: one float4 lane per slice element (192 blocks x
// 256 threads = 49152 = STEP_STRIDE/4). Each thread loads its element of the
// frozen slice out[tf] ONCE (786 KB total vs R10's 165 MB of re-reads) and
// streams it to slices tf+1..maxit-1 (each block writes a contiguous 4 KB
// burst per slice). Also overwrites any overshoot slices the stepper wrote
// past the freeze. Pure write-bound: ~165 MB @ ~6 TB/s ~= 27 us.
__global__ void fill_kernel(const int* __restrict__ flags,
                            float4* __restrict__ out,
                            int total4)
{
    const int s4 = STEP_STRIDE / 4;
    const int maxit = total4 / s4;
    const int ds = flags[F_DONE];
    const int tf = (ds >= 1 && ds <= maxit - 1) ? ds : maxit - 1;
    const int idx = (int)blockIdx.x * (int)blockDim.x + (int)threadIdx.x;
    const float4 v = out[(size_t)tf * s4 + idx];
    for (int t = tf + 1; t < maxit; ++t)
        out[(size_t)t * s4 + idx] = v;
}

extern "C" void kernel_launch(void* const* d_in, const int* in_sizes, int n_in,
                              void* d_out, int out_size, void* d_ws, size_t ws_size,
                              hipStream_t stream)
{
    const float* D   = (const float*)d_in[0];
    const int* sx    = (const int*)d_in[1];
    const int* sy    = (const int*)d_in[2];
    const int* sz    = (const int*)d_in[3];
    const int* ex    = (const int*)d_in[4];
    const int* ey    = (const int*)d_in[5];
    const int* ez    = (const int*)d_in[6];
    const int* maxit = (const int*)d_in[7];
    float* out = (float*)d_out;

    u64* ring  = (u64*)d_ws;                   // 2 x 3 x 32768 x 8B = 1.6 MB
    int* flags = (int*)(ring + RING_WORDS);

    // 128 blocks x 256 threads (x-plane x y-stripe); plain launch, tagged
    // dataflow sync. Co-residency by capacity (128 blocks << 256 CUs).
    BEMNA_V7_2_PhaseSpace_44117904064519_kernel<<<dim3(NBLOCKS), dim3(NTHREADS), 0, stream>>>(
        D, sx, sy, sz, ex, ey, ez, maxit, out, ring, flags);

    // one float4 lane per slice element: STEP_STRIDE/4 = 49152 threads
    const int total4 = out_size / 4;
    fill_kernel<<<dim3((STEP_STRIDE / 4) / 256), dim3(256), 0, stream>>>(
        flags, (float4*)out, total4);
}